// Round 2
// baseline (52.560 us; speedup 1.0000x reference)
//
#include <hip/hip_runtime.h>
#include <hip/hip_cooperative_groups.h>

namespace cg = cooperative_groups;

#define T_LEN 65536
// x: [T, B=2, DIN=4] f32 ; ih: [4,5] ; hh: [5,5] ; bias: [5] ; out: scalar f32
// out = sum_t ((sum_b x_t[b])@ih + 2*bias) . w_{T-1-t},   w_s = hh^s @ ones
// s = 65535 - t = 256*(255 - blockIdx.x) + (255 - tid)   (grid 256x256)
//   -> high byte block-uniform, low byte per-thread.

__global__ __launch_bounds__(256) void elman_sum_kernel(
    const float* __restrict__ x, const float* __restrict__ ih,
    const float* __restrict__ hh, const float* __restrict__ bias,
    float* __restrict__ out, float* __restrict__ partials)
{
    __shared__ float sP[16][25];   // sP[k] = hh^(2^k), row-major 5x5
    __shared__ float sih[20];      // ih row-major [4][5]
    __shared__ float sb5[5];
    __shared__ float red[4];

    const int tid = threadIdx.x;
    const int t   = blockIdx.x * 256 + tid;

    // Issue global loads immediately: HBM latency hides under the squaring.
    const float4* x4 = (const float4*)x;
    const float4 r0 = x4[2*t];
    const float4 r1 = x4[2*t + 1];

    // Wave 0: repeated squaring entirely in-register via shuffles (no barriers).
    // Lanes 0..24 hold element (i,j); all 64 lanes run the shuffles.
    if (tid < 64) {
        const int i5 = (tid < 25) ? (tid / 5) * 5 : 0;
        const int j  = (tid < 25) ? (tid % 5)     : 0;
        float m = (tid < 25) ? hh[tid] : 0.f;
        if (tid < 25) sP[0][tid] = m;
        #pragma unroll
        for (int k = 1; k < 16; ++k) {
            const float a0 = __shfl(m, i5 + 0, 64);
            const float a1 = __shfl(m, i5 + 1, 64);
            const float a2 = __shfl(m, i5 + 2, 64);
            const float a3 = __shfl(m, i5 + 3, 64);
            const float a4 = __shfl(m, i5 + 4, 64);
            const float b0 = __shfl(m,  0 + j, 64);
            const float b1 = __shfl(m,  5 + j, 64);
            const float b2 = __shfl(m, 10 + j, 64);
            const float b3 = __shfl(m, 15 + j, 64);
            const float b4 = __shfl(m, 20 + j, 64);
            m = a0*b0 + a1*b1 + a2*b2 + a3*b3 + a4*b4;
            if (tid < 25) sP[k][tid] = m;
        }
    } else if (tid < 128) {
        const int q = tid - 64;
        if (q < 20) sih[q] = ih[q];
        else if (q < 25) sb5[q - 20] = bias[q - 20];
    }
    __syncthreads();   // the only intra-block barrier before the reduce

    // y = hh^(256*s_hi) @ ones — block-uniform, uniform branches (no divergence)
    const unsigned shi = 255u - blockIdx.x;
    float y0 = 1.f, y1 = 1.f, y2 = 1.f, y3 = 1.f, y4 = 1.f;
    #pragma unroll
    for (int k = 0; k < 8; ++k) {
        if ((shi >> k) & 1u) {
            const float* P = sP[8 + k];
            const float n0 = P[ 0]*y0 + P[ 1]*y1 + P[ 2]*y2 + P[ 3]*y3 + P[ 4]*y4;
            const float n1 = P[ 5]*y0 + P[ 6]*y1 + P[ 7]*y2 + P[ 8]*y3 + P[ 9]*y4;
            const float n2 = P[10]*y0 + P[11]*y1 + P[12]*y2 + P[13]*y3 + P[14]*y4;
            const float n3 = P[15]*y0 + P[16]*y1 + P[17]*y2 + P[18]*y3 + P[19]*y4;
            const float n4 = P[20]*y0 + P[21]*y1 + P[22]*y2 + P[23]*y3 + P[24]*y4;
            y0 = n0; y1 = n1; y2 = n2; y3 = n3; y4 = n4;
        }
    }

    // w = hh^s_lo @ y — per-thread low byte, branchless selects
    const unsigned slo = 255u - (unsigned)tid;
    float w0 = y0, w1 = y1, w2 = y2, w3 = y3, w4 = y4;
    #pragma unroll
    for (int k = 0; k < 8; ++k) {
        const float* P = sP[k];
        const float n0 = P[ 0]*w0 + P[ 1]*w1 + P[ 2]*w2 + P[ 3]*w3 + P[ 4]*w4;
        const float n1 = P[ 5]*w0 + P[ 6]*w1 + P[ 7]*w2 + P[ 8]*w3 + P[ 9]*w4;
        const float n2 = P[10]*w0 + P[11]*w1 + P[12]*w2 + P[13]*w3 + P[14]*w4;
        const float n3 = P[15]*w0 + P[16]*w1 + P[17]*w2 + P[18]*w3 + P[19]*w4;
        const float n4 = P[20]*w0 + P[21]*w1 + P[22]*w2 + P[23]*w3 + P[24]*w4;
        const bool take = (slo >> k) & 1u;
        w0 = take ? n0 : w0;
        w1 = take ? n1 : w1;
        w2 = take ? n2 : w2;
        w3 = take ? n3 : w3;
        w4 = take ? n4 : w4;
    }

    // contrib = ((sum_b x_t[b])@ih + 2*bias) . w
    const float xs0 = r0.x + r1.x, xs1 = r0.y + r1.y;
    const float xs2 = r0.z + r1.z, xs3 = r0.w + r1.w;
    const float u0 = 2.f*sb5[0] + xs0*sih[0] + xs1*sih[5] + xs2*sih[10] + xs3*sih[15];
    const float u1 = 2.f*sb5[1] + xs0*sih[1] + xs1*sih[6] + xs2*sih[11] + xs3*sih[16];
    const float u2 = 2.f*sb5[2] + xs0*sih[2] + xs1*sih[7] + xs2*sih[12] + xs3*sih[17];
    const float u3 = 2.f*sb5[3] + xs0*sih[3] + xs1*sih[8] + xs2*sih[13] + xs3*sih[18];
    const float u4 = 2.f*sb5[4] + xs0*sih[4] + xs1*sih[9] + xs2*sih[14] + xs3*sih[19];
    float contrib = u0*w0 + u1*w1 + u2*w2 + u3*w3 + u4*w4;

    // wave64 shuffle reduce -> per-wave LDS -> per-block partial
    #pragma unroll
    for (int off = 32; off > 0; off >>= 1)
        contrib += __shfl_down(contrib, off, 64);
    if ((tid & 63) == 0) red[tid >> 6] = contrib;
    __syncthreads();
    if (tid == 0) {
        partials[blockIdx.x] = red[0] + red[1] + red[2] + red[3];
        __threadfence();   // make partial visible device-wide before grid sync
    }

    cg::this_grid().sync();

    // block 0 reduces the 256 partials and writes the scalar (no atomics,
    // no zero-init needed -> no memset dispatch in the graph)
    if (blockIdx.x == 0) {
        float v = partials[tid];
        #pragma unroll
        for (int off = 32; off > 0; off >>= 1)
            v += __shfl_down(v, off, 64);
        if ((tid & 63) == 0) red[tid >> 6] = v;
        __syncthreads();
        if (tid == 0) out[0] = red[0] + red[1] + red[2] + red[3];
    }
}

extern "C" void kernel_launch(void* const* d_in, const int* in_sizes, int n_in,
                              void* d_out, int out_size, void* d_ws, size_t ws_size,
                              hipStream_t stream) {
    const float* x    = (const float*)d_in[0];
    const float* ih   = (const float*)d_in[1];
    const float* hh   = (const float*)d_in[2];
    const float* bias = (const float*)d_in[3];
    float* out      = (float*)d_out;
    float* partials = (float*)d_ws;   // 256 floats, fully overwritten each call

    void* args[] = { (void*)&x, (void*)&ih, (void*)&hh, (void*)&bias,
                     (void*)&out, (void*)&partials };
    hipLaunchCooperativeKernel((const void*)elman_sum_kernel,
                               dim3(T_LEN / 256), dim3(256), args, 0, stream);
}

// Round 3
// 16.540 us; speedup vs baseline: 3.1778x; 3.1778x over previous
//
#include <hip/hip_runtime.h>

#define T_LEN 65536
// x: [T, B=2, DIN=4] f32 ; ih: [4,5] ; hh: [5,5] ; bias: [5] ; out: scalar f32
// out = sum_t ((sum_b x_t[b])@ih + 2*bias) . w_{T-1-t},   w_s = hh^s @ ones
// s = 65535 - t,  t = 256*blockIdx + tid :
//   bits 8..15 of s = 255 - blockIdx   (block-uniform  -> coherent branches)
//   bits 6..7  of s = 3   - (tid>>6)   (wave-uniform   -> coherent branches)
//   bits 0..5  of s = 63  - (tid&63)   (per-lane       -> branchless selects)
// All factors are powers of hh -> they commute; application order is free.

__global__ __launch_bounds__(256) void elman_sum_kernel(
    const float* __restrict__ x, const float* __restrict__ ih,
    const float* __restrict__ hh, const float* __restrict__ bias,
    float* __restrict__ out)
{
    __shared__ float sP[16][25];   // sP[k] = hh^(2^k), row-major 5x5
    __shared__ float sih[20];      // ih row-major [4][5]
    __shared__ float sb5[5];
    __shared__ float red[4];

    const int tid = threadIdx.x;
    const int t   = blockIdx.x * 256 + tid;

    // Issue global loads first: HBM latency hides under the squaring chain.
    const float4* x4 = (const float4*)x;
    const float4 r0 = x4[2*t];
    const float4 r1 = x4[2*t + 1];

    // Wave 0: repeated squaring entirely in-register via shuffles (no barriers).
    if (tid < 64) {
        const int i5 = (tid < 25) ? (tid / 5) * 5 : 0;
        const int j  = (tid < 25) ? (tid % 5)     : 0;
        float m = (tid < 25) ? hh[tid] : 0.f;
        if (tid < 25) sP[0][tid] = m;
        #pragma unroll
        for (int k = 1; k < 16; ++k) {
            const float a0 = __shfl(m, i5 + 0, 64);
            const float a1 = __shfl(m, i5 + 1, 64);
            const float a2 = __shfl(m, i5 + 2, 64);
            const float a3 = __shfl(m, i5 + 3, 64);
            const float a4 = __shfl(m, i5 + 4, 64);
            const float b0 = __shfl(m,  0 + j, 64);
            const float b1 = __shfl(m,  5 + j, 64);
            const float b2 = __shfl(m, 10 + j, 64);
            const float b3 = __shfl(m, 15 + j, 64);
            const float b4 = __shfl(m, 20 + j, 64);
            m = a0*b0 + a1*b1 + a2*b2 + a3*b3 + a4*b4;
            if (tid < 25) sP[k][tid] = m;
        }
    } else if (tid < 128) {
        const int q = tid - 64;
        if (q < 20) sih[q] = ih[q];
        else if (q < 25) sb5[q - 20] = bias[q - 20];
    }
    __syncthreads();   // the only barrier before the reduce

#define MATVEC(P, c0, c1, c2, c3, c4)                                          \
    {                                                                          \
        const float n0 = P[ 0]*c0 + P[ 1]*c1 + P[ 2]*c2 + P[ 3]*c3 + P[ 4]*c4;\
        const float n1 = P[ 5]*c0 + P[ 6]*c1 + P[ 7]*c2 + P[ 8]*c3 + P[ 9]*c4;\
        const float n2 = P[10]*c0 + P[11]*c1 + P[12]*c2 + P[13]*c3 + P[14]*c4;\
        const float n3 = P[15]*c0 + P[16]*c1 + P[17]*c2 + P[18]*c3 + P[19]*c4;\
        const float n4 = P[20]*c0 + P[21]*c1 + P[22]*c2 + P[23]*c3 + P[24]*c4;\
        c0 = n0; c1 = n1; c2 = n2; c3 = n3; c4 = n4;                           \
    }

    float w0 = 1.f, w1 = 1.f, w2 = 1.f, w3 = 1.f, w4 = 1.f;

    // bits 8..15: block-uniform, coherent branches (avg 4 matvecs)
    const unsigned shi = 255u - blockIdx.x;
    #pragma unroll
    for (int k = 0; k < 8; ++k) {
        if ((shi >> k) & 1u) {
            const float* P = sP[8 + k];
            MATVEC(P, w0, w1, w2, w3, w4);
        }
    }

    // bits 6..7: wave-uniform, coherent branches (avg 1 matvec)
    const unsigned wlo = 3u - (unsigned)(tid >> 6);
    if (wlo & 1u) { const float* P = sP[6]; MATVEC(P, w0, w1, w2, w3, w4); }
    if (wlo & 2u) { const float* P = sP[7]; MATVEC(P, w0, w1, w2, w3, w4); }

    // bits 0..5: per-lane, branchless selects; fully unrolled so the compiler
    // can hoist all LDS broadcast reads early.
    const unsigned llo = 63u - (unsigned)(tid & 63);
    #pragma unroll
    for (int k = 0; k < 6; ++k) {
        const float* P = sP[k];
        const float n0 = P[ 0]*w0 + P[ 1]*w1 + P[ 2]*w2 + P[ 3]*w3 + P[ 4]*w4;
        const float n1 = P[ 5]*w0 + P[ 6]*w1 + P[ 7]*w2 + P[ 8]*w3 + P[ 9]*w4;
        const float n2 = P[10]*w0 + P[11]*w1 + P[12]*w2 + P[13]*w3 + P[14]*w4;
        const float n3 = P[15]*w0 + P[16]*w1 + P[17]*w2 + P[18]*w3 + P[19]*w4;
        const float n4 = P[20]*w0 + P[21]*w1 + P[22]*w2 + P[23]*w3 + P[24]*w4;
        const bool take = (llo >> k) & 1u;
        w0 = take ? n0 : w0;
        w1 = take ? n1 : w1;
        w2 = take ? n2 : w2;
        w3 = take ? n3 : w3;
        w4 = take ? n4 : w4;
    }

    // contrib = ((sum_b x_t[b])@ih + 2*bias) . w
    const float xs0 = r0.x + r1.x, xs1 = r0.y + r1.y;
    const float xs2 = r0.z + r1.z, xs3 = r0.w + r1.w;
    const float u0 = 2.f*sb5[0] + xs0*sih[0] + xs1*sih[5] + xs2*sih[10] + xs3*sih[15];
    const float u1 = 2.f*sb5[1] + xs0*sih[1] + xs1*sih[6] + xs2*sih[11] + xs3*sih[16];
    const float u2 = 2.f*sb5[2] + xs0*sih[2] + xs1*sih[7] + xs2*sih[12] + xs3*sih[17];
    const float u3 = 2.f*sb5[3] + xs0*sih[3] + xs1*sih[8] + xs2*sih[13] + xs3*sih[18];
    const float u4 = 2.f*sb5[4] + xs0*sih[4] + xs1*sih[9] + xs2*sih[14] + xs3*sih[19];
    float contrib = u0*w0 + u1*w1 + u2*w2 + u3*w3 + u4*w4;

    // wave64 shuffle reduce -> per-wave LDS -> one atomic per block
    #pragma unroll
    for (int off = 32; off > 0; off >>= 1)
        contrib += __shfl_down(contrib, off, 64);
    if ((tid & 63) == 0) red[tid >> 6] = contrib;
    __syncthreads();
    if (tid == 0) {
        atomicAdd(out, red[0] + red[1] + red[2] + red[3]);
    }
#undef MATVEC
}

extern "C" void kernel_launch(void* const* d_in, const int* in_sizes, int n_in,
                              void* d_out, int out_size, void* d_ws, size_t ws_size,
                              hipStream_t stream) {
    const float* x    = (const float*)d_in[0];
    const float* ih   = (const float*)d_in[1];
    const float* hh   = (const float*)d_in[2];
    const float* bias = (const float*)d_in[3];
    float* out = (float*)d_out;

    // atomicAdd accumulator must start at zero each call (harness poisons
    // d_out once and never re-zeroes between graph replays).
    hipMemsetAsync(out, 0, sizeof(float), stream);

    elman_sum_kernel<<<T_LEN / 256, 256, 0, stream>>>(x, ih, hh, bias, out);
}

// Round 4
// 14.944 us; speedup vs baseline: 3.5172x; 1.1068x over previous
//
#include <hip/hip_runtime.h>

#define T_LEN 65536
// x: [T, B=2, DIN=4] f32 ; ih: [4,5] ; hh: [5,5] ; bias: [5] ; out: scalar f32
// out = sum_t ((sum_b x_t[b])@ih + 2*bias) . w_{T-1-t},   w_s = hh^s @ ones
//
// Grid 64 x 256, each thread handles 4 timesteps:
//   t = 16384*m + 256*b + tid,  m = 3..0
//   s = 65535 - t = 16384*(3-m) + 256*(63-b) + (255-tid)   (borrow-free)
// Per-thread: build w for m=3 from block bits (sP[8..13], uniform branches),
// wave bits (sP[6..7]), lane bits (sP[0..5], branchless selects); then chain
// m=2,1,0 via w <- hh^16384 @ w = sP[14] @ w. Powers of hh commute.

__global__ __launch_bounds__(256) void elman_sum_kernel(
    const float* __restrict__ x, const float* __restrict__ ih,
    const float* __restrict__ hh, const float* __restrict__ bias,
    float* __restrict__ out)
{
    __shared__ float sP[15][25];   // sP[k] = hh^(2^k), row-major 5x5
    __shared__ float sih[20];      // ih row-major [4][5]
    __shared__ float sb5[5];
    __shared__ float red[4];

    const int tid = threadIdx.x;
    const int b   = blockIdx.x;

    // Issue all 8 global loads first: HBM latency hides under the squaring.
    const float4* x4 = (const float4*)x;
    float4 ra[4], rb[4];
    #pragma unroll
    for (int j = 0; j < 4; ++j) {
        const int t = (3 - j) * 16384 + (b << 8) + tid;
        ra[j] = x4[2 * t];
        rb[j] = x4[2 * t + 1];
    }

    // Wave 0: repeated squaring entirely in-register via shuffles (no barriers).
    if (tid < 64) {
        const int i5 = (tid < 25) ? (tid / 5) * 5 : 0;
        const int j  = (tid < 25) ? (tid % 5)     : 0;
        float m = (tid < 25) ? hh[tid] : 0.f;
        if (tid < 25) sP[0][tid] = m;
        #pragma unroll
        for (int k = 1; k < 15; ++k) {
            const float a0 = __shfl(m, i5 + 0, 64);
            const float a1 = __shfl(m, i5 + 1, 64);
            const float a2 = __shfl(m, i5 + 2, 64);
            const float a3 = __shfl(m, i5 + 3, 64);
            const float a4 = __shfl(m, i5 + 4, 64);
            const float b0 = __shfl(m,  0 + j, 64);
            const float b1 = __shfl(m,  5 + j, 64);
            const float b2 = __shfl(m, 10 + j, 64);
            const float b3 = __shfl(m, 15 + j, 64);
            const float b4 = __shfl(m, 20 + j, 64);
            m = a0*b0 + a1*b1 + a2*b2 + a3*b3 + a4*b4;
            if (tid < 25) sP[k][tid] = m;
        }
    } else if (tid < 128) {
        const int q = tid - 64;
        if (q < 20) sih[q] = ih[q];
        else if (q < 25) sb5[q - 20] = bias[q - 20];
    }
    __syncthreads();   // the only barrier before the reduce

#define MATVEC(P, c0, c1, c2, c3, c4)                                          \
    {                                                                          \
        const float n0 = P[ 0]*c0 + P[ 1]*c1 + P[ 2]*c2 + P[ 3]*c3 + P[ 4]*c4;\
        const float n1 = P[ 5]*c0 + P[ 6]*c1 + P[ 7]*c2 + P[ 8]*c3 + P[ 9]*c4;\
        const float n2 = P[10]*c0 + P[11]*c1 + P[12]*c2 + P[13]*c3 + P[14]*c4;\
        const float n3 = P[15]*c0 + P[16]*c1 + P[17]*c2 + P[18]*c3 + P[19]*c4;\
        const float n4 = P[20]*c0 + P[21]*c1 + P[22]*c2 + P[23]*c3 + P[24]*c4;\
        c0 = n0; c1 = n1; c2 = n2; c3 = n3; c4 = n4;                           \
    }

    float w0 = 1.f, w1 = 1.f, w2 = 1.f, w3 = 1.f, w4 = 1.f;

    // lane bits 0..5 of s: (255-tid)&63 — branchless selects, unconditional
    // instruction stream starts right at the barrier.
    const unsigned llo = 255u - (unsigned)tid;   // bits 0..5 used
    #pragma unroll
    for (int k = 0; k < 6; ++k) {
        const float* P = sP[k];
        const float n0 = P[ 0]*w0 + P[ 1]*w1 + P[ 2]*w2 + P[ 3]*w3 + P[ 4]*w4;
        const float n1 = P[ 5]*w0 + P[ 6]*w1 + P[ 7]*w2 + P[ 8]*w3 + P[ 9]*w4;
        const float n2 = P[10]*w0 + P[11]*w1 + P[12]*w2 + P[13]*w3 + P[14]*w4;
        const float n3 = P[15]*w0 + P[16]*w1 + P[17]*w2 + P[18]*w3 + P[19]*w4;
        const float n4 = P[20]*w0 + P[21]*w1 + P[22]*w2 + P[23]*w3 + P[24]*w4;
        const bool take = (llo >> k) & 1u;
        w0 = take ? n0 : w0;
        w1 = take ? n1 : w1;
        w2 = take ? n2 : w2;
        w3 = take ? n3 : w3;
        w4 = take ? n4 : w4;
    }

    // wave bits 6..7 of s: 3 - (tid>>6) — wave-uniform coherent branches
    const unsigned wlo = 3u - (unsigned)(tid >> 6);
    if (wlo & 1u) { const float* P = sP[6]; MATVEC(P, w0, w1, w2, w3, w4); }
    if (wlo & 2u) { const float* P = sP[7]; MATVEC(P, w0, w1, w2, w3, w4); }

    // block bits 8..13 of s: 63 - b — block-uniform coherent branches (avg 3)
    const unsigned shi = 63u - (unsigned)b;
    #pragma unroll
    for (int k = 0; k < 6; ++k) {
        if ((shi >> k) & 1u) {
            const float* P = sP[8 + k];
            MATVEC(P, w0, w1, w2, w3, w4);
        }
    }

    // 4 timesteps per thread; chain s += 16384 via sP[14]
    float acc = 0.f;
    #pragma unroll
    for (int j = 0; j < 4; ++j) {
        if (j > 0) { const float* P = sP[14]; MATVEC(P, w0, w1, w2, w3, w4); }
        const float xs0 = ra[j].x + rb[j].x, xs1 = ra[j].y + rb[j].y;
        const float xs2 = ra[j].z + rb[j].z, xs3 = ra[j].w + rb[j].w;
        const float u0 = 2.f*sb5[0] + xs0*sih[0] + xs1*sih[5] + xs2*sih[10] + xs3*sih[15];
        const float u1 = 2.f*sb5[1] + xs0*sih[1] + xs1*sih[6] + xs2*sih[11] + xs3*sih[16];
        const float u2 = 2.f*sb5[2] + xs0*sih[2] + xs1*sih[7] + xs2*sih[12] + xs3*sih[17];
        const float u3 = 2.f*sb5[3] + xs0*sih[3] + xs1*sih[8] + xs2*sih[13] + xs3*sih[18];
        const float u4 = 2.f*sb5[4] + xs0*sih[4] + xs1*sih[9] + xs2*sih[14] + xs3*sih[19];
        acc += u0*w0 + u1*w1 + u2*w2 + u3*w3 + u4*w4;
    }

    // wave64 shuffle reduce -> per-wave LDS -> one atomic per block (64 total)
    #pragma unroll
    for (int off = 32; off > 0; off >>= 1)
        acc += __shfl_down(acc, off, 64);
    if ((tid & 63) == 0) red[tid >> 6] = acc;
    __syncthreads();
    if (tid == 0) {
        atomicAdd(out, red[0] + red[1] + red[2] + red[3]);
    }
#undef MATVEC
}

extern "C" void kernel_launch(void* const* d_in, const int* in_sizes, int n_in,
                              void* d_out, int out_size, void* d_ws, size_t ws_size,
                              hipStream_t stream) {
    const float* x    = (const float*)d_in[0];
    const float* ih   = (const float*)d_in[1];
    const float* hh   = (const float*)d_in[2];
    const float* bias = (const float*)d_in[3];
    float* out = (float*)d_out;

    // atomicAdd accumulator must start at zero each call. Any memset-free
    // scheme (counter/epoch) breaks on the first call when buffers hold
    // poison, so this 4-byte fill node is structurally required.
    hipMemsetAsync(out, 0, sizeof(float), stream);

    elman_sum_kernel<<<64, 256, 0, stream>>>(x, ih, hh, bias, out);
}

// Round 5
// 13.217 us; speedup vs baseline: 3.9768x; 1.1307x over previous
//
#include <hip/hip_runtime.h>

#define T_LEN 65536
// x: [T, B=2, DIN=4] f32 ; ih: [4,5] ; hh: [5,5] ; bias: [5] ; out: scalar f32
// out = sum_t ((sum_b x_t[b])@ih + 2*bias) . w_{T-1-t},   w_s = hh^s @ ones
//
// Grid 64 x 256, each thread handles 4 timesteps:
//   t = 16384*m + 256*b + tid,  m = 3..0
//   s = 65535 - t = 16384*(3-m) + 256*(63-b) + (255-tid)   (borrow-free)
// Powers of hh commute -> apply block bits (sP[8..13], uniform branches),
// wave bits (sP[6..7]), lane bits (sP[0..5], branchless selects), then chain
// m=2,1,0 via w <- sP[14] @ w.
//
// Completion: fence+counter "last block" reduction, poison-proof:
//   old = atomicAdd(cnt,1); last iff (old & 63) == 63 — holds for ANY initial
//   cnt (64 consecutive ints contain exactly one ==63 mod 64), so the first
//   call (cnt = 0xAAAAAAAA poison) works; finisher resets cnt=0 so all later
//   calls/replays are deterministic. No memset node, no atomics on out.

__global__ __launch_bounds__(256) void elman_sum_kernel(
    const float* __restrict__ x, const float* __restrict__ ih,
    const float* __restrict__ hh, const float* __restrict__ bias,
    float* __restrict__ out, float* __restrict__ partials,
    unsigned* __restrict__ cnt)
{
    __shared__ float sP[15][25];   // sP[k] = hh^(2^k), row-major 5x5
    __shared__ float sih[20];      // ih row-major [4][5]
    __shared__ float sb5[5];
    __shared__ float red[4];

    const int tid = threadIdx.x;
    const int b   = blockIdx.x;

    // Issue all 8 global loads first: HBM latency hides under the squaring.
    const float4* x4 = (const float4*)x;
    float4 ra[4], rb[4];
    #pragma unroll
    for (int j = 0; j < 4; ++j) {
        const int t = (3 - j) * 16384 + (b << 8) + tid;
        ra[j] = x4[2 * t];
        rb[j] = x4[2 * t + 1];
    }

    // Wave 0: repeated squaring entirely in-register via shuffles (no barriers).
    if (tid < 64) {
        const int i5 = (tid < 25) ? (tid / 5) * 5 : 0;
        const int j  = (tid < 25) ? (tid % 5)     : 0;
        float m = (tid < 25) ? hh[tid] : 0.f;
        if (tid < 25) sP[0][tid] = m;
        #pragma unroll
        for (int k = 1; k < 15; ++k) {
            const float a0 = __shfl(m, i5 + 0, 64);
            const float a1 = __shfl(m, i5 + 1, 64);
            const float a2 = __shfl(m, i5 + 2, 64);
            const float a3 = __shfl(m, i5 + 3, 64);
            const float a4 = __shfl(m, i5 + 4, 64);
            const float b0 = __shfl(m,  0 + j, 64);
            const float b1 = __shfl(m,  5 + j, 64);
            const float b2 = __shfl(m, 10 + j, 64);
            const float b3 = __shfl(m, 15 + j, 64);
            const float b4 = __shfl(m, 20 + j, 64);
            m = a0*b0 + a1*b1 + a2*b2 + a3*b3 + a4*b4;
            if (tid < 25) sP[k][tid] = m;
        }
    } else if (tid < 128) {
        const int q = tid - 64;
        if (q < 20) sih[q] = ih[q];
        else if (q < 25) sb5[q - 20] = bias[q - 20];
    }
    __syncthreads();   // the only barrier before the reduce

#define MATVEC(P, c0, c1, c2, c3, c4)                                          \
    {                                                                          \
        const float n0 = P[ 0]*c0 + P[ 1]*c1 + P[ 2]*c2 + P[ 3]*c3 + P[ 4]*c4;\
        const float n1 = P[ 5]*c0 + P[ 6]*c1 + P[ 7]*c2 + P[ 8]*c3 + P[ 9]*c4;\
        const float n2 = P[10]*c0 + P[11]*c1 + P[12]*c2 + P[13]*c3 + P[14]*c4;\
        const float n3 = P[15]*c0 + P[16]*c1 + P[17]*c2 + P[18]*c3 + P[19]*c4;\
        const float n4 = P[20]*c0 + P[21]*c1 + P[22]*c2 + P[23]*c3 + P[24]*c4;\
        c0 = n0; c1 = n1; c2 = n2; c3 = n3; c4 = n4;                           \
    }

    float w0 = 1.f, w1 = 1.f, w2 = 1.f, w3 = 1.f, w4 = 1.f;

    // lane bits 0..5 of s — branchless selects
    const unsigned llo = 255u - (unsigned)tid;   // bits 0..5 used
    #pragma unroll
    for (int k = 0; k < 6; ++k) {
        const float* P = sP[k];
        const float n0 = P[ 0]*w0 + P[ 1]*w1 + P[ 2]*w2 + P[ 3]*w3 + P[ 4]*w4;
        const float n1 = P[ 5]*w0 + P[ 6]*w1 + P[ 7]*w2 + P[ 8]*w3 + P[ 9]*w4;
        const float n2 = P[10]*w0 + P[11]*w1 + P[12]*w2 + P[13]*w3 + P[14]*w4;
        const float n3 = P[15]*w0 + P[16]*w1 + P[17]*w2 + P[18]*w3 + P[19]*w4;
        const float n4 = P[20]*w0 + P[21]*w1 + P[22]*w2 + P[23]*w3 + P[24]*w4;
        const bool take = (llo >> k) & 1u;
        w0 = take ? n0 : w0;
        w1 = take ? n1 : w1;
        w2 = take ? n2 : w2;
        w3 = take ? n3 : w3;
        w4 = take ? n4 : w4;
    }

    // wave bits 6..7 of s — wave-uniform coherent branches
    const unsigned wlo = 3u - (unsigned)(tid >> 6);
    if (wlo & 1u) { const float* P = sP[6]; MATVEC(P, w0, w1, w2, w3, w4); }
    if (wlo & 2u) { const float* P = sP[7]; MATVEC(P, w0, w1, w2, w3, w4); }

    // block bits 8..13 of s — block-uniform coherent branches (avg 3)
    const unsigned shi = 63u - (unsigned)b;
    #pragma unroll
    for (int k = 0; k < 6; ++k) {
        if ((shi >> k) & 1u) {
            const float* P = sP[8 + k];
            MATVEC(P, w0, w1, w2, w3, w4);
        }
    }

    // 4 timesteps per thread; chain s += 16384 via sP[14]
    float acc = 0.f;
    #pragma unroll
    for (int j = 0; j < 4; ++j) {
        if (j > 0) { const float* P = sP[14]; MATVEC(P, w0, w1, w2, w3, w4); }
        const float xs0 = ra[j].x + rb[j].x, xs1 = ra[j].y + rb[j].y;
        const float xs2 = ra[j].z + rb[j].z, xs3 = ra[j].w + rb[j].w;
        const float u0 = 2.f*sb5[0] + xs0*sih[0] + xs1*sih[5] + xs2*sih[10] + xs3*sih[15];
        const float u1 = 2.f*sb5[1] + xs0*sih[1] + xs1*sih[6] + xs2*sih[11] + xs3*sih[16];
        const float u2 = 2.f*sb5[2] + xs0*sih[2] + xs1*sih[7] + xs2*sih[12] + xs3*sih[17];
        const float u3 = 2.f*sb5[3] + xs0*sih[3] + xs1*sih[8] + xs2*sih[13] + xs3*sih[18];
        const float u4 = 2.f*sb5[4] + xs0*sih[4] + xs1*sih[9] + xs2*sih[14] + xs3*sih[19];
        acc += u0*w0 + u1*w1 + u2*w2 + u3*w3 + u4*w4;
    }
#undef MATVEC

    // wave64 shuffle reduce -> per-wave LDS -> block partial
    #pragma unroll
    for (int off = 32; off > 0; off >>= 1)
        acc += __shfl_down(acc, off, 64);
    if ((tid & 63) == 0) red[tid >> 6] = acc;
    __syncthreads();

    // release partial, bump counter; unique last block finishes
    int am_last = 0;
    if (tid == 0) {
        partials[b] = red[0] + red[1] + red[2] + red[3];
        __threadfence();                       // release: partial visible first
        const unsigned old = atomicAdd(cnt, 1u);
        am_last = ((old & 63u) == 63u) ? 1 : 0;
    }
    am_last = __shfl(am_last, 0, 64);          // broadcast within wave 0
    if (tid < 64 && am_last) {
        __threadfence();                       // acquire: see all partials
        float v = partials[tid];
        #pragma unroll
        for (int off = 32; off > 0; off >>= 1)
            v += __shfl_down(v, off, 64);
        if (tid == 0) {
            out[0] = v;
            *cnt = 0;                          // deterministic state for next call
        }
    }
}

extern "C" void kernel_launch(void* const* d_in, const int* in_sizes, int n_in,
                              void* d_out, int out_size, void* d_ws, size_t ws_size,
                              hipStream_t stream) {
    const float* x    = (const float*)d_in[0];
    const float* ih   = (const float*)d_in[1];
    const float* hh   = (const float*)d_in[2];
    const float* bias = (const float*)d_in[3];
    float*    out      = (float*)d_out;
    float*    partials = (float*)d_ws;            // 64 floats
    unsigned* cnt      = (unsigned*)d_ws + 64;    // 1 u32 (any init value OK)

    elman_sum_kernel<<<64, 256, 0, stream>>>(x, ih, hh, bias, out, partials, cnt);
}